// Round 6
// baseline (58.265 us; speedup 1.0000x reference)
//
#include <hip/hip_runtime.h>

#define V   1024
#define NH  16384
#define NM  16384

#define BAND_LOW_MAX    500.0f
#define BAND_MID_MAX    2000.0f
#define ENERGY_THRESHOLD 0.5f

// clang native vector type (required by __builtin_nontemporal_*)
typedef float f32x4 __attribute__((ext_vector_type(4)));

// ---------------------------------------------------------------------------
// Kernel 1: per-voice band stats. One block per voice.
// stats planar [5][V]: {E_low*af, E_mid*af, E_high*af, cw*af, af}
// Regular caching loads: harm should stay L3-resident for kernel 2's re-read.
// ---------------------------------------------------------------------------
__global__ __launch_bounds__(256)
void k1_stats(const float* __restrict__ harm,
              const float* __restrict__ f0_hz,
              const float* __restrict__ cw,
              const int*   __restrict__ is_active,
              float* __restrict__ stats /* [5][V] */) {
    const int v   = blockIdx.x;
    const int tid = threadIdx.x;
    const float f0 = f0_hz[v];
    const f32x4* hrow = (const f32x4*)harm + (size_t)v * 4096;

    float e0 = 0.f, e1 = 0.f, e2 = 0.f;
    #pragma unroll
    for (int k = 0; k < 16; ++k) {
        const f32x4 a = hrow[tid + k * 256];
        const int hbase = (tid + k * 256) * 4;
        #pragma unroll
        for (int j = 0; j < 4; ++j) {
            const float freq = f0 * (float)(hbase + j + 1);  // fp32 mul, matches jnp
            if (freq < BAND_LOW_MAX)       e0 += a[j];
            else if (freq < BAND_MID_MAX)  e1 += a[j];
            else                           e2 += a[j];
        }
    }
    for (int off = 32; off > 0; off >>= 1) {
        e0 += __shfl_down(e0, off);
        e1 += __shfl_down(e1, off);
        e2 += __shfl_down(e2, off);
    }
    __shared__ float s[3][4];
    const int wid  = tid >> 6;
    const int lane = tid & 63;
    if (lane == 0) { s[0][wid] = e0; s[1][wid] = e1; s[2][wid] = e2; }
    __syncthreads();
    if (tid == 0) {
        const float t0 = s[0][0] + s[0][1] + s[0][2] + s[0][3];
        const float t1 = s[1][0] + s[1][1] + s[1][2] + s[1][3];
        const float t2 = s[2][0] + s[2][1] + s[2][2] + s[2][3];
        const float af = (is_active[v] != 0) ? 1.0f : 0.0f;
        stats[0 * V + v] = t0 * af;
        stats[1 * V + v] = t1 * af;
        stats[2 * V + v] = t2 * af;
        stats[3 * V + v] = cw[v] * af;
        stats[4 * V + v] = af;
    }
}

// ---------------------------------------------------------------------------
// Kernel 2: fused totals-reduce + gains + elementwise apply, grid-stride.
// 2048 blocks x 256 threads = 8192 waves (exactly fills all wave slots).
// Each block reduces the [5][V] stats ONCE (voice-independent totals,
// deterministic fixed tree), then streams 4 segments of 1024 f32x4.
// Segment seg = v*8 + part; parts 0-3 = harm quarter-rows, 4-7 = noise.
// Per-segment gains are ~20 scalar ops (cheap, recomputed per segment).
// ---------------------------------------------------------------------------
__global__ __launch_bounds__(256)
void k2_apply(const float* __restrict__ harm,
              const float* __restrict__ noise,
              const float* __restrict__ f0_hz,
              const float* __restrict__ cw,
              const float* __restrict__ wd,
              const int*   __restrict__ is_active,
              const float* __restrict__ stats,
              float* __restrict__ out) {
    const int tid = threadIdx.x;

    // ---- totals over stats: plane p is 1024 floats = 256 f32x4 -----------
    const f32x4* sp = (const f32x4*)stats;
    const f32x4 x0 = sp[0 * 256 + tid];
    const f32x4 x1 = sp[1 * 256 + tid];
    const f32x4 x2 = sp[2 * 256 + tid];
    const f32x4 x3 = sp[3 * 256 + tid];
    const f32x4 x4 = sp[4 * 256 + tid];
    float r0 = (x0[0] + x0[1]) + (x0[2] + x0[3]);
    float r1 = (x1[0] + x1[1]) + (x1[2] + x1[3]);
    float r2 = (x2[0] + x2[1]) + (x2[2] + x2[3]);
    float r3 = (x3[0] + x3[1]) + (x3[2] + x3[3]);
    float r4 = (x4[0] + x4[1]) + (x4[2] + x4[3]);
    for (int off = 32; off > 0; off >>= 1) {
        r0 += __shfl_down(r0, off);
        r1 += __shfl_down(r1, off);
        r2 += __shfl_down(r2, off);
        r3 += __shfl_down(r3, off);
        r4 += __shfl_down(r4, off);
    }
    __shared__ float s2[5][4];
    const int wid  = tid >> 6;
    const int lane = tid & 63;
    if (lane == 0) {
        s2[0][wid] = r0; s2[1][wid] = r1; s2[2][wid] = r2;
        s2[3][wid] = r3; s2[4][wid] = r4;
    }
    __syncthreads();
    const float TE[3] = {
        s2[0][0] + s2[0][1] + s2[0][2] + s2[0][3],
        s2[1][0] + s2[1][1] + s2[1][2] + s2[1][3],
        s2[2][0] + s2[2][1] + s2[2][2] + s2[2][3] };
    const float TW = s2[3][0] + s2[3][1] + s2[3][2] + s2[3][3];
    const float NA = s2[4][0] + s2[4][1] + s2[4][2] + s2[4][3];
    const bool changed = (NA >= 1.5f);               // n_active >= 2

    // ---- grid-stride over 4 segments --------------------------------------
    #pragma unroll
    for (int s = 0; s < 4; ++s) {
        const int seg  = blockIdx.x + s * 2048;      // 0..8191
        const int v    = seg >> 3;
        const int part = seg & 7;

        // per-voice gains (block-uniform scalar loads; cheap)
        const bool  act   = (is_active[v] != 0);
        const float w     = cw[v];
        const float share = (w / fmaxf(TW, 1e-6f)) * ENERGY_THRESHOLD;
        const float ea[3] = { stats[0 * V + v], stats[1 * V + v], stats[2 * V + v] };

        const float tbefore = ea[0] + ea[1] + ea[2];
        float tafter = 0.f;
        float g[3];
        #pragma unroll
        for (int b = 0; b < 3; ++b) {
            const float excess = ea[b] - share;
            const float exr    = excess / fmaxf(ea[b], 1e-6f);
            const float red    = fmaxf(0.3f, 1.0f - wd[v * 3 + b] * exr * 0.5f);
            const bool apply   = (TE[b] > ENERGY_THRESHOLD) && (ea[b] > 0.0f) &&
                                 (excess > 0.0f) && act;
            const float gb = apply ? red : 1.0f;
            tafter += gb * ea[b];
            g[b] = changed ? gb : 1.0f;
        }
        const float nscale = (tbefore > 1e-6f) ? (tafter / tbefore) : 1.0f;
        const float nse    = (changed && act) ? nscale : 1.0f;
        const float g0 = g[0], g1 = g[1], g2 = g[2];

        f32x4* orow = (f32x4*)out + (size_t)v * 8192;
        if (part < 4) {
            const float f0 = f0_hz[v];
            const f32x4* hrow = (const f32x4*)harm + (size_t)v * 4096;
            const int c0 = part * 1024 + tid;
            #pragma unroll
            for (int k = 0; k < 4; ++k) {
                const int c = c0 + k * 256;
                const f32x4 a = hrow[c];
                f32x4 o;
                #pragma unroll
                for (int j = 0; j < 4; ++j) {
                    const float freq = f0 * (float)(c * 4 + j + 1);
                    const float gg = (freq < BAND_LOW_MAX) ? g0
                                   : (freq < BAND_MID_MAX) ? g1 : g2;
                    o[j] = a[j] * gg;
                }
                __builtin_nontemporal_store(o, orow + c);
            }
        } else {
            const f32x4* nrow = (const f32x4*)noise + (size_t)v * 4096;
            const int c0 = (part - 4) * 1024 + tid;
            #pragma unroll
            for (int k = 0; k < 4; ++k) {
                const int c = c0 + k * 256;
                const f32x4 n = nrow[c];
                __builtin_nontemporal_store(n * nse, orow + 4096 + c);
            }
        }
    }
}

// ---------------------------------------------------------------------------
extern "C" void kernel_launch(void* const* d_in, const int* in_sizes, int n_in,
                              void* d_out, int out_size, void* d_ws, size_t ws_size,
                              hipStream_t stream) {
    const float* harm  = (const float*)d_in[0];
    const float* noise = (const float*)d_in[1];
    const float* f0    = (const float*)d_in[2];
    const float* cw    = (const float*)d_in[3];
    const float* wd    = (const float*)d_in[4];
    const int*   act   = (const int*)d_in[5];
    float* out   = (float*)d_out;
    float* stats = (float*)d_ws;   // 5*V floats

    k1_stats<<<V, 256, 0, stream>>>(harm, f0, cw, act, stats);
    k2_apply<<<2048, 256, 0, stream>>>(harm, noise, f0, cw, wd, act, stats, out);
}